// Round 11
// baseline (175.553 us; speedup 1.0000x reference)
//
#include <hip/hip_runtime.h>
#include <cstdint>
#include <cstddef>

#define B 4096
#define D 128
#define MARGIN_F 0.2f
#define CW 256            // per-row candidate capacity
#define ROWS 8            // rows per block (74KB LDS -> 2 blocks/CU)
#define SSTR 4104         // key-strip stride (ushorts)

typedef short bf16x8 __attribute__((ext_vector_type(8)));
typedef float f32x4 __attribute__((ext_vector_type(4)));
typedef uint32_t u32x4 __attribute__((ext_vector_type(4)));

// order-preserving float->uint (ascending uint == ascending float)
__device__ __forceinline__ uint32_t xform_key(float f) {
    uint32_t u = __float_as_uint(f);
    return u ^ (uint32_t)((((int32_t)u) >> 31) | 0x80000000);
}
// decode 16-bit truncated key (bucket center under round-to-nearest encode)
__device__ __forceinline__ float unxform16(uint32_t k16) {
    uint32_t u = k16 << 16;
    u = (u & 0x80000000u) ? (u ^ 0x80000000u) : ~u;
    return __uint_as_float(u);
}
__device__ __forceinline__ unsigned short f2bf(float f) {   // round-nearest-even
    uint32_t u = __float_as_uint(f);
    return (unsigned short)((u + 0x7FFFu + ((u >> 16) & 1u)) >> 16);
}

// fused: zero out, sq[i] = ||R[i]||^2, R -> Rb (bf16 rne)
__global__ __launch_bounds__(256) void prep_kernel(const float* __restrict__ R,
                                                   float* __restrict__ sq,
                                                   unsigned short* __restrict__ Rb,
                                                   float* __restrict__ out) {
    if (blockIdx.x == 0 && threadIdx.x == 0) out[0] = 0.0f;
    int wave = threadIdx.x >> 6;
    int lane = threadIdx.x & 63;
    int row  = blockIdx.x * 4 + wave;
    const float2* R2 = (const float2*)R + (size_t)row * (D / 2);
    float2 v = R2[lane];
    ushort2 o; o.x = f2bf(v.x); o.y = f2bf(v.y);
    *(ushort2*)(Rb + (size_t)row * D + lane * 2) = o;
    float s = v.x * v.x + v.y * v.y;
#pragma unroll
    for (int off = 32; off > 0; off >>= 1) s += __shfl_down(s, off);
    if (lane == 0) sq[row] = s;
}

// FUSED, 8 rows/block, 2 blocks/CU (16 waves/CU — 2x r10's residency).
// Phase 1: MFMA gram (A rows duplicated t&7; epilogue keeps rows 0..7) ->
// 16-bit keys in 65.7KB LDS strip. Phase 2: one wave per row, r8 machinery.
__global__ __launch_bounds__(512, 4) void fused_loss(const unsigned short* __restrict__ Rb,
                                                     const float* __restrict__ sq,
                                                     const int* __restrict__ labels,
                                                     float* __restrict__ out) {
    __shared__ unsigned short S[ROWS * SSTR];      // 65,664 B key strip
    __shared__ uint32_t cand_c[ROWS][CW];          // 8 KB: comb | (match<<31)
    __shared__ int cnt[ROWS];

    const int tid  = threadIdx.x;
    const int wid  = tid >> 6, lane = tid & 63;
    const int q    = lane >> 4, t = lane & 15;
    const int r0   = blockIdx.x * ROWS;

    if (tid < ROWS) cnt[tid] = 0;

    // ---- phase 1: A fragments (rows t&7, duplicated into M=8..15)
    bf16x8 af[4];
    const unsigned short* baseA = Rb + (size_t)(r0 + (t & 7)) * D + q * 8;
#pragma unroll
    for (int kq = 0; kq < 4; ++kq)
        af[kq] = *(const bf16x8*)(baseA + kq * 32);

    float sqa[4]; int la[4];                       // row scalars for rows (q*4+rr)&7
#pragma unroll
    for (int rr = 0; rr < 4; ++rr) {
        sqa[rr] = sq[r0 + ((q * 4 + rr) & 7)];
        la[rr]  = labels[r0 + ((q * 4 + rr) & 7)];
    }

    // 256 j-tiles of 16 cols; 8 waves -> 32 tiles/wave
    for (int i = 0; i < 32; ++i) {
        const int jt  = wid * 32 + i;
        const int col = jt * 16 + t;
        const unsigned short* baseB = Rb + (size_t)col * D + q * 8;
        bf16x8 bfr[4];
#pragma unroll
        for (int kq = 0; kq < 4; ++kq)
            bfr[kq] = *(const bf16x8*)(baseB + kq * 32);
        f32x4 acc = (f32x4)0.0f;
#pragma unroll
        for (int kq = 0; kq < 4; ++kq)
            acc = __builtin_amdgcn_mfma_f32_16x16x32_bf16(af[kq], bfr[kq], acc, 0, 0, 0);

        if (q < 2) {                               // rows q*4+rr in 0..7 are real
            const float sqc = sq[col];
            const int   lc  = labels[col];
#pragma unroll
            for (int rr = 0; rr < 4; ++rr) {       // D: row = q*4+rr, col = t
                float g  = acc[rr];
                float d2 = fmaxf(sqa[rr] + sqc - 2.0f * g, 0.0f);
                float dist = (d2 > 0.0f) ? sqrtf(d2) : 0.0f;
                float s = -dist + ((la[rr] == lc) ? 0.0f : MARGIN_F);
                uint32_t key = xform_key(s);       // sim <= 0.2 -> no ovf on +0x8000
                S[(q * 4 + rr) * SSTR + col] = (unsigned short)((key + 0x8000u) >> 16);
            }
        }
    }
    __syncthreads();                               // strip complete; cnt[] visible

    // ---- phase 2: one wave per row; keys kv[8] from LDS (b128, aligned)
    float facc = 0.0f;
    const int4* lv = (const int4*)labels;
    {
        const int row  = wid;
        const int grow = r0 + row;
        const int li   = labels[grow];

        u32x4 kv[8];
#pragma unroll
        for (int qq = 0; qq < 8; ++qq)
            kv[qq] = *(u32x4*)(&S[row * SSTR + (qq * 64 + lane) * 8]);

        uint64_t mbits = 0;
        uint32_t t1 = 0, t2 = 0;
#pragma unroll
        for (int qq = 0; qq < 8; ++qq) {
            const int lb = (qq * 64 + lane) * 2;
            int4 la4 = lv[lb], lc4 = lv[lb + 1];
            uint32_t u[8] = {kv[qq].x & 0xFFFFu, kv[qq].x >> 16,
                             kv[qq].y & 0xFFFFu, kv[qq].y >> 16,
                             kv[qq].z & 0xFFFFu, kv[qq].z >> 16,
                             kv[qq].w & 0xFFFFu, kv[qq].w >> 16};
#pragma unroll
            for (int c = 0; c < 8; ++c) {
                uint32_t mn = min(t1, u[c]);
                t1 = max(t1, u[c]);
                t2 = max(t2, mn);
            }
            mbits |= (uint64_t)(la4.x == li) << (qq * 8 + 0);
            mbits |= (uint64_t)(la4.y == li) << (qq * 8 + 1);
            mbits |= (uint64_t)(la4.z == li) << (qq * 8 + 2);
            mbits |= (uint64_t)(la4.w == li) << (qq * 8 + 3);
            mbits |= (uint64_t)(lc4.x == li) << (qq * 8 + 4);
            mbits |= (uint64_t)(lc4.y == li) << (qq * 8 + 5);
            mbits |= (uint64_t)(lc4.z == li) << (qq * 8 + 6);
            mbits |= (uint64_t)(lc4.w == li) << (qq * 8 + 7);
        }

        int kloc = __popcll(mbits);
#pragma unroll
        for (int off = 32; off > 0; off >>= 1) kloc += __shfl_xor(kloc, off);
        const int k = kloc;
        const float kf = (float)k;

        // ballot binary search: T = k-th largest of 128-subset (<= true k-th)
        const int kneed = min(k, 128);
        uint32_t T = 0;
#pragma unroll
        for (int b = 15; b >= 0; --b) {
            uint32_t g = T | (1u << b);
            int c = __popcll(__ballot(t1 >= g)) + __popcll(__ballot(t2 >= g));
            if (c >= kneed) T = g;
        }
        const uint32_t combT = T << 12;

        // gather candidates = {u >= T} U {matches}; comb = (u<<12)|(4095-j)
#pragma unroll
        for (int qq = 0; qq < 8; ++qq) {
            uint32_t u[8] = {kv[qq].x & 0xFFFFu, kv[qq].x >> 16,
                             kv[qq].y & 0xFFFFu, kv[qq].y >> 16,
                             kv[qq].z & 0xFFFFu, kv[qq].z >> 16,
                             kv[qq].w & 0xFFFFu, kv[qq].w >> 16};
            int jb = (qq * 64 + lane) * 8;
#pragma unroll
            for (int c = 0; c < 8; ++c) {
                int e = qq * 8 + c;
                uint32_t m = (uint32_t)((mbits >> e) & 1);
                if (u[c] >= T || m) {
                    int p = atomicAdd(&cnt[row], 1);
                    if (p < CW)
                        cand_c[row][p] = (u[c] << 12) | (uint32_t)(4095 - (jb + c)) | (m << 31);
                }
            }
        }
        const int ncand = min(cnt[row], CW);

        // candidate-internal exact ranks for u >= T (every beater is a candidate)
        for (int s = lane; s < ncand; s += 64) {
            uint32_t cs = cand_c[row][s];
            uint32_t comb = cs & 0x7FFFFFFFu;
            int m = (int)(cs >> 31);
            if (comb >= combT) {
                int c2 = 0;
                for (int c = 0; c < ncand; ++c)
                    c2 += ((cand_c[row][c] & 0x7FFFFFFFu) > comb) ? 1 : 0;
                int rank = 1 + c2;
                float v = unxform16(comb >> 12);
                if (!m && rank <= k)
                    facc += v * (0.5f + ((kf - (float)rank + 1.0f) / kf) * 0.5f);
                else if (m && rank > k)
                    facc -= v * (0.5f + (((float)rank - kf) / (float)(B - k)) * 0.5f);
            }
        }

        // below-T matches (rank > k guaranteed): register scans, batch 4
        uint32_t p0 = 0xFFFFFFFFu, p1 = 0xFFFFFFFFu, p2 = 0xFFFFFFFFu, p3 = 0xFFFFFFFFu;
        int np = 0;
        for (int c = 0; c <= ncand; ++c) {
            bool flushit = (c == ncand);
            if (!flushit) {
                uint32_t cc_ = cand_c[row][c];
                if ((cc_ & 0x80000000u) && (cc_ & 0x7FFFFFFFu) < combT) {
                    uint32_t comb = cc_ & 0x7FFFFFFFu;
                    if (np == 0) p0 = comb; else if (np == 1) p1 = comb;
                    else if (np == 2) p2 = comb; else p3 = comb;
                    ++np;
                    flushit = (np == 4);
                }
            }
            if (flushit && np > 0) {
                int c0 = 0, c1 = 0, c2 = 0, c3 = 0;
#pragma unroll
                for (int qq = 0; qq < 8; ++qq) {
                    uint32_t u[8] = {kv[qq].x & 0xFFFFu, kv[qq].x >> 16,
                                     kv[qq].y & 0xFFFFu, kv[qq].y >> 16,
                                     kv[qq].z & 0xFFFFu, kv[qq].z >> 16,
                                     kv[qq].w & 0xFFFFu, kv[qq].w >> 16};
                    int jb = (qq * 64 + lane) * 8;
#pragma unroll
                    for (int cc = 0; cc < 8; ++cc) {
                        uint32_t comb_e = (u[cc] << 12) | (uint32_t)(4095 - (jb + cc));
                        c0 += (comb_e > p0) ? 1 : 0;
                        c1 += (comb_e > p1) ? 1 : 0;
                        c2 += (comb_e > p2) ? 1 : 0;
                        c3 += (comb_e > p3) ? 1 : 0;
                    }
                }
#pragma unroll
                for (int off = 32; off > 0; off >>= 1) {
                    c0 += __shfl_xor(c0, off); c1 += __shfl_xor(c1, off);
                    c2 += __shfl_xor(c2, off); c3 += __shfl_xor(c3, off);
                }
                if (lane == 0) {
                    int rk[4] = {1 + c0, 1 + c1, 1 + c2, 1 + c3};
                    uint32_t pp[4] = {p0, p1, p2, p3};
                    for (int ii = 0; ii < np; ++ii) {
                        float v = unxform16(pp[ii] >> 12);
                        facc -= v * (0.5f + (((float)rk[ii] - kf) / (float)(B - k)) * 0.5f);
                    }
                }
                p0 = p1 = p2 = p3 = 0xFFFFFFFFu;
                np = 0;
            }
        }
    }

#pragma unroll
    for (int off = 32; off > 0; off >>= 1) facc += __shfl_xor(facc, off);
    if (lane == 0) atomicAdd(out, facc);
}

extern "C" void kernel_launch(void* const* d_in, const int* in_sizes, int n_in,
                              void* d_out, int out_size, void* d_ws, size_t ws_size,
                              hipStream_t stream) {
    const float* R      = (const float*)d_in[0];
    const int*   labels = (const int*)d_in[1];
    float* out = (float*)d_out;

    float*          sq = (float*)d_ws;                               // 16 KB
    unsigned short* Rb = (unsigned short*)((char*)d_ws + 16 * 1024); // 1 MB

    hipLaunchKernelGGL(prep_kernel, dim3(B / 4), dim3(256), 0, stream, R, sq, Rb, out);
    hipLaunchKernelGGL(fused_loss, dim3(B / ROWS), dim3(512), 0, stream,
                       Rb, sq, labels, out);
}

// Round 12
// 149.195 us; speedup vs baseline: 1.1767x; 1.1767x over previous
//
#include <hip/hip_runtime.h>
#include <cstdint>
#include <cstddef>

#define B 4096
#define D 128
#define MARGIN_F 0.2f
#define CW 256            // per-row candidate capacity
#define ROWS 16           // rows per block
#define SSTR 4104         // key-strip stride (ushorts)

typedef short bf16x8 __attribute__((ext_vector_type(8)));
typedef float f32x4 __attribute__((ext_vector_type(4)));
typedef uint32_t u32x4 __attribute__((ext_vector_type(4)));

// order-preserving float->uint (ascending uint == ascending float)
__device__ __forceinline__ uint32_t xform_key(float f) {
    uint32_t u = __float_as_uint(f);
    return u ^ (uint32_t)((((int32_t)u) >> 31) | 0x80000000);
}
// decode 16-bit truncated key (bucket center under round-to-nearest encode)
__device__ __forceinline__ float unxform16(uint32_t k16) {
    uint32_t u = k16 << 16;
    u = (u & 0x80000000u) ? (u ^ 0x80000000u) : ~u;
    return __uint_as_float(u);
}
__device__ __forceinline__ unsigned short f2bf(float f) {   // round-nearest-even
    uint32_t u = __float_as_uint(f);
    return (unsigned short)((u + 0x7FFFu + ((u >> 16) & 1u)) >> 16);
}

// fused prep: zero out; sq; R->Rb bf16; match-bit mask in phase-2 lane layout.
// mask64[l*64+lane] bit (qq*8+c) = (labels[qq*512+lane*8+c] == l)
__global__ __launch_bounds__(256) void prep_kernel(const float* __restrict__ R,
                                                   const int* __restrict__ labels,
                                                   float* __restrict__ sq,
                                                   unsigned short* __restrict__ Rb,
                                                   unsigned long long* __restrict__ mask64,
                                                   float* __restrict__ out) {
    if (blockIdx.x == 0 && threadIdx.x == 0) out[0] = 0.0f;
    int wave = threadIdx.x >> 6;
    int lane = threadIdx.x & 63;
    int row  = blockIdx.x * 4 + wave;
    const float2* R2 = (const float2*)R + (size_t)row * (D / 2);
    float2 v = R2[lane];
    ushort2 o; o.x = f2bf(v.x); o.y = f2bf(v.y);
    *(ushort2*)(Rb + (size_t)row * D + lane * 2) = o;
    float s = v.x * v.x + v.y * v.y;
#pragma unroll
    for (int off = 32; off > 0; off >>= 1) s += __shfl_down(s, off);
    if (lane == 0) sq[row] = s;

    // 32768 (label,lane) pairs over 1024 blocks: 32 per block
    if (threadIdx.x < 32) {
        int p  = blockIdx.x * 32 + threadIdx.x;
        int l  = p >> 6;
        int ln = p & 63;
        unsigned long long m = 0ull;
#pragma unroll
        for (int qq = 0; qq < 8; ++qq) {
            int jb = qq * 512 + ln * 8;
#pragma unroll
            for (int c = 0; c < 8; ++c)
                m |= (unsigned long long)(labels[jb + c] == l) << (qq * 8 + c);
        }
        mask64[(size_t)l * 64 + ln] = m;
    }
}

// FUSED, r10 work-shape (ROWS=16, grid 256, 1 block/CU) but 16 waves/block:
// same per-CU work as r10 at 2x the latency hiding (4 waves/SIMD).
__global__ __launch_bounds__(1024, 4) void fused_loss(const unsigned short* __restrict__ Rb,
                                                      const float* __restrict__ sq,
                                                      const int* __restrict__ labels,
                                                      const unsigned long long* __restrict__ mask64,
                                                      float* __restrict__ out) {
    __shared__ unsigned short S[ROWS * SSTR];      // 131,328 B key strip
    __shared__ uint32_t cand_c[ROWS][CW];          // 16 KB: comb | (match<<31)
    __shared__ int cnt[ROWS];

    const int tid  = threadIdx.x;
    const int wid  = tid >> 6, lane = tid & 63;
    const int q    = lane >> 4, t = lane & 15;
    const int r0   = blockIdx.x * ROWS;

    if (tid < ROWS) cnt[tid] = 0;

    // ---- phase 1: A fragments for the block's 16 rows
    bf16x8 af[4];
    const unsigned short* baseA = Rb + (size_t)(r0 + t) * D + q * 8;
#pragma unroll
    for (int kq = 0; kq < 4; ++kq)
        af[kq] = *(const bf16x8*)(baseA + kq * 32);

    float sqa[4]; int la[4];                       // epilogue row scalars (row = q*4+rr)
#pragma unroll
    for (int rr = 0; rr < 4; ++rr) {
        sqa[rr] = sq[r0 + q * 4 + rr];
        la[rr]  = labels[r0 + q * 4 + rr];
    }

    // 256 j-tiles of 16 cols; 16 waves -> 16 tiles/wave, unrolled x2
    for (int i = 0; i < 16; i += 2) {
        const int col0 = (wid * 16 + i) * 16 + t;
        const int col1 = col0 + 16;
        const unsigned short* b0 = Rb + (size_t)col0 * D + q * 8;
        const unsigned short* b1 = Rb + (size_t)col1 * D + q * 8;
        bf16x8 f0[4], f1[4];
#pragma unroll
        for (int kq = 0; kq < 4; ++kq) f0[kq] = *(const bf16x8*)(b0 + kq * 32);
#pragma unroll
        for (int kq = 0; kq < 4; ++kq) f1[kq] = *(const bf16x8*)(b1 + kq * 32);
        const float sqc0 = sq[col0], sqc1 = sq[col1];
        const int   lc0  = labels[col0], lc1 = labels[col1];

        f32x4 a0 = (f32x4)0.0f, a1 = (f32x4)0.0f;
#pragma unroll
        for (int kq = 0; kq < 4; ++kq)
            a0 = __builtin_amdgcn_mfma_f32_16x16x32_bf16(af[kq], f0[kq], a0, 0, 0, 0);
#pragma unroll
        for (int kq = 0; kq < 4; ++kq)
            a1 = __builtin_amdgcn_mfma_f32_16x16x32_bf16(af[kq], f1[kq], a1, 0, 0, 0);

#pragma unroll
        for (int rr = 0; rr < 4; ++rr) {           // D: row = q*4+rr, col = t
            float d20 = fmaxf(sqa[rr] + sqc0 - 2.0f * a0[rr], 0.0f);
            float di0 = (d20 > 0.0f) ? sqrtf(d20) : 0.0f;
            float s0 = -di0 + ((la[rr] == lc0) ? 0.0f : MARGIN_F);
            S[(q * 4 + rr) * SSTR + col0] =
                (unsigned short)((xform_key(s0) + 0x8000u) >> 16);
            float d21 = fmaxf(sqa[rr] + sqc1 - 2.0f * a1[rr], 0.0f);
            float di1 = (d21 > 0.0f) ? sqrtf(d21) : 0.0f;
            float s1 = -di1 + ((la[rr] == lc1) ? 0.0f : MARGIN_F);
            S[(q * 4 + rr) * SSTR + col1] =
                (unsigned short)((xform_key(s1) + 0x8000u) >> 16);
        }
    }
    __syncthreads();                               // strip complete; cnt[] visible

    // ---- phase 2: one wave per row; keys kv[8] from LDS; mbits precomputed
    float facc = 0.0f;
    {
        const int row  = wid;
        const int grow = r0 + row;
        const int li   = labels[grow];

        const uint64_t mbits = mask64[(size_t)li * 64 + lane];

        u32x4 kv[8];
#pragma unroll
        for (int qq = 0; qq < 8; ++qq)
            kv[qq] = *(u32x4*)(&S[row * SSTR + (qq * 64 + lane) * 8]);

        uint32_t t1 = 0, t2 = 0;
#pragma unroll
        for (int qq = 0; qq < 8; ++qq) {
            uint32_t u[8] = {kv[qq].x & 0xFFFFu, kv[qq].x >> 16,
                             kv[qq].y & 0xFFFFu, kv[qq].y >> 16,
                             kv[qq].z & 0xFFFFu, kv[qq].z >> 16,
                             kv[qq].w & 0xFFFFu, kv[qq].w >> 16};
#pragma unroll
            for (int c = 0; c < 8; ++c) {
                uint32_t mn = min(t1, u[c]);
                t1 = max(t1, u[c]);
                t2 = max(t2, mn);
            }
        }

        int kloc = __popcll(mbits);
#pragma unroll
        for (int off = 32; off > 0; off >>= 1) kloc += __shfl_xor(kloc, off);
        const int k = kloc;
        const float kf = (float)k;

        // ballot binary search: T = k-th largest of 128-subset (<= true k-th)
        const int kneed = min(k, 128);
        uint32_t T = 0;
#pragma unroll
        for (int b = 15; b >= 0; --b) {
            uint32_t g = T | (1u << b);
            int c = __popcll(__ballot(t1 >= g)) + __popcll(__ballot(t2 >= g));
            if (c >= kneed) T = g;
        }
        const uint32_t combT = T << 12;

        // gather candidates = {u >= T} U {matches}; comb = (u<<12)|(4095-j)
#pragma unroll
        for (int qq = 0; qq < 8; ++qq) {
            uint32_t u[8] = {kv[qq].x & 0xFFFFu, kv[qq].x >> 16,
                             kv[qq].y & 0xFFFFu, kv[qq].y >> 16,
                             kv[qq].z & 0xFFFFu, kv[qq].z >> 16,
                             kv[qq].w & 0xFFFFu, kv[qq].w >> 16};
            int jb = (qq * 64 + lane) * 8;
#pragma unroll
            for (int c = 0; c < 8; ++c) {
                int e = qq * 8 + c;
                uint32_t m = (uint32_t)((mbits >> e) & 1);
                if (u[c] >= T || m) {
                    int p = atomicAdd(&cnt[row], 1);
                    if (p < CW)
                        cand_c[row][p] = (u[c] << 12) | (uint32_t)(4095 - (jb + c)) | (m << 31);
                }
            }
        }
        const int ncand = min(cnt[row], CW);

        // candidate-internal exact ranks for u >= T (every beater is a candidate)
        for (int s = lane; s < ncand; s += 64) {
            uint32_t cs = cand_c[row][s];
            uint32_t comb = cs & 0x7FFFFFFFu;
            int m = (int)(cs >> 31);
            if (comb >= combT) {
                int c2 = 0;
                for (int c = 0; c < ncand; ++c)
                    c2 += ((cand_c[row][c] & 0x7FFFFFFFu) > comb) ? 1 : 0;
                int rank = 1 + c2;
                float v = unxform16(comb >> 12);
                if (!m && rank <= k)
                    facc += v * (0.5f + ((kf - (float)rank + 1.0f) / kf) * 0.5f);
                else if (m && rank > k)
                    facc -= v * (0.5f + (((float)rank - kf) / (float)(B - k)) * 0.5f);
            }
        }

        // below-T matches (rank > k guaranteed): register scans, batch 4
        uint32_t p0 = 0xFFFFFFFFu, p1 = 0xFFFFFFFFu, p2 = 0xFFFFFFFFu, p3 = 0xFFFFFFFFu;
        int np = 0;
        for (int c = 0; c <= ncand; ++c) {
            bool flushit = (c == ncand);
            if (!flushit) {
                uint32_t cc_ = cand_c[row][c];
                if ((cc_ & 0x80000000u) && (cc_ & 0x7FFFFFFFu) < combT) {
                    uint32_t comb = cc_ & 0x7FFFFFFFu;
                    if (np == 0) p0 = comb; else if (np == 1) p1 = comb;
                    else if (np == 2) p2 = comb; else p3 = comb;
                    ++np;
                    flushit = (np == 4);
                }
            }
            if (flushit && np > 0) {
                int c0 = 0, c1 = 0, c2 = 0, c3 = 0;
#pragma unroll
                for (int qq = 0; qq < 8; ++qq) {
                    uint32_t u[8] = {kv[qq].x & 0xFFFFu, kv[qq].x >> 16,
                                     kv[qq].y & 0xFFFFu, kv[qq].y >> 16,
                                     kv[qq].z & 0xFFFFu, kv[qq].z >> 16,
                                     kv[qq].w & 0xFFFFu, kv[qq].w >> 16};
                    int jb = (qq * 64 + lane) * 8;
#pragma unroll
                    for (int cc = 0; cc < 8; ++cc) {
                        uint32_t comb_e = (u[cc] << 12) | (uint32_t)(4095 - (jb + cc));
                        c0 += (comb_e > p0) ? 1 : 0;
                        c1 += (comb_e > p1) ? 1 : 0;
                        c2 += (comb_e > p2) ? 1 : 0;
                        c3 += (comb_e > p3) ? 1 : 0;
                    }
                }
#pragma unroll
                for (int off = 32; off > 0; off >>= 1) {
                    c0 += __shfl_xor(c0, off); c1 += __shfl_xor(c1, off);
                    c2 += __shfl_xor(c2, off); c3 += __shfl_xor(c3, off);
                }
                if (lane == 0) {
                    int rk[4] = {1 + c0, 1 + c1, 1 + c2, 1 + c3};
                    uint32_t pp[4] = {p0, p1, p2, p3};
                    for (int ii = 0; ii < np; ++ii) {
                        float v = unxform16(pp[ii] >> 12);
                        facc -= v * (0.5f + (((float)rk[ii] - kf) / (float)(B - k)) * 0.5f);
                    }
                }
                p0 = p1 = p2 = p3 = 0xFFFFFFFFu;
                np = 0;
            }
        }
    }

#pragma unroll
    for (int off = 32; off > 0; off >>= 1) facc += __shfl_xor(facc, off);
    if (lane == 0) atomicAdd(out, facc);
}

extern "C" void kernel_launch(void* const* d_in, const int* in_sizes, int n_in,
                              void* d_out, int out_size, void* d_ws, size_t ws_size,
                              hipStream_t stream) {
    const float* R      = (const float*)d_in[0];
    const int*   labels = (const int*)d_in[1];
    float* out = (float*)d_out;

    float*              sq   = (float*)d_ws;                                 // 16 KB
    unsigned short*     Rb   = (unsigned short*)((char*)d_ws + 16 * 1024);   // 1 MB
    unsigned long long* mask = (unsigned long long*)((char*)d_ws + 16 * 1024 + 1024 * 1024);

    hipLaunchKernelGGL(prep_kernel, dim3(B / 4), dim3(256), 0, stream,
                       R, labels, sq, Rb, mask, out);
    hipLaunchKernelGGL(fused_loss, dim3(B / ROWS), dim3(1024), 0, stream,
                       Rb, sq, labels, mask, out);
}

// Round 13
// 139.099 us; speedup vs baseline: 1.2621x; 1.0726x over previous
//
#include <hip/hip_runtime.h>
#include <cstdint>
#include <cstddef>

#define B 4096
#define D 128
#define MARGIN_F 0.2f
#define CW 256            // per-row candidate capacity
#define ROWS 16           // rows per block (r10 shape: grid 256, 8 waves)
#define SSTR 4104         // key-strip stride (ushorts)

typedef short bf16x8 __attribute__((ext_vector_type(8)));
typedef float f32x4 __attribute__((ext_vector_type(4)));
typedef uint32_t u32x4 __attribute__((ext_vector_type(4)));

// order-preserving float->uint (ascending uint == ascending float)
__device__ __forceinline__ uint32_t xform_key(float f) {
    uint32_t u = __float_as_uint(f);
    return u ^ (uint32_t)((((int32_t)u) >> 31) | 0x80000000);
}
// decode 16-bit truncated key (bucket center under round-to-nearest encode)
__device__ __forceinline__ float unxform16(uint32_t k16) {
    uint32_t u = k16 << 16;
    u = (u & 0x80000000u) ? (u ^ 0x80000000u) : ~u;
    return __uint_as_float(u);
}
__device__ __forceinline__ unsigned short f2bf(float f) {   // round-nearest-even
    uint32_t u = __float_as_uint(f);
    return (unsigned short)((u + 0x7FFFu + ((u >> 16) & 1u)) >> 16);
}

// fused prep: zero out; sq; R->Rb bf16; match-bit mask in phase-2 lane layout.
// mask64[l*64+lane] bit (qq*8+c) = (labels[qq*512+lane*8+c] == l)
__global__ __launch_bounds__(256) void prep_kernel(const float* __restrict__ R,
                                                   const int* __restrict__ labels,
                                                   float* __restrict__ sq,
                                                   unsigned short* __restrict__ Rb,
                                                   unsigned long long* __restrict__ mask64,
                                                   float* __restrict__ out) {
    if (blockIdx.x == 0 && threadIdx.x == 0) out[0] = 0.0f;
    int wave = threadIdx.x >> 6;
    int lane = threadIdx.x & 63;
    int row  = blockIdx.x * 4 + wave;
    const float2* R2 = (const float2*)R + (size_t)row * (D / 2);
    float2 v = R2[lane];
    ushort2 o; o.x = f2bf(v.x); o.y = f2bf(v.y);
    *(ushort2*)(Rb + (size_t)row * D + lane * 2) = o;
    float s = v.x * v.x + v.y * v.y;
#pragma unroll
    for (int off = 32; off > 0; off >>= 1) s += __shfl_down(s, off);
    if (lane == 0) sq[row] = s;

    // 32768 (label,lane) pairs over 1024 blocks: 32 per block
    if (threadIdx.x < 32) {
        int p  = blockIdx.x * 32 + threadIdx.x;
        int l  = p >> 6;
        int ln = p & 63;
        unsigned long long m = 0ull;
#pragma unroll
        for (int qq = 0; qq < 8; ++qq) {
            int jb = qq * 512 + ln * 8;
#pragma unroll
            for (int c = 0; c < 8; ++c)
                m |= (unsigned long long)(labels[jb + c] == l) << (qq * 8 + c);
        }
        mask64[(size_t)l * 64 + ln] = m;
    }
}

// FUSED, r10 shape (ROWS=16, grid 256, 8 waves, 2 rows/wave in phase 2),
// + phase-1 unroll-2 load pipelining, + precomputed masks, + 8-wide fn batches.
__global__ __launch_bounds__(512) void fused_loss(const unsigned short* __restrict__ Rb,
                                                  const float* __restrict__ sq,
                                                  const int* __restrict__ labels,
                                                  const unsigned long long* __restrict__ mask64,
                                                  float* __restrict__ out) {
    __shared__ unsigned short S[ROWS * SSTR];      // 131,328 B key strip
    __shared__ uint32_t cand_c[ROWS][CW];          // 16 KB: comb | (match<<31)
    __shared__ int cnt[ROWS];

    const int tid  = threadIdx.x;
    const int wid  = tid >> 6, lane = tid & 63;
    const int q    = lane >> 4, t = lane & 15;
    const int r0   = blockIdx.x * ROWS;

    if (tid < ROWS) cnt[tid] = 0;

    // ---- phase 1: A fragments for the block's 16 rows
    bf16x8 af[4];
    const unsigned short* baseA = Rb + (size_t)(r0 + t) * D + q * 8;
#pragma unroll
    for (int kq = 0; kq < 4; ++kq)
        af[kq] = *(const bf16x8*)(baseA + kq * 32);

    float sqa[4]; int la[4];                       // epilogue row scalars (row = q*4+rr)
#pragma unroll
    for (int rr = 0; rr < 4; ++rr) {
        sqa[rr] = sq[r0 + q * 4 + rr];
        la[rr]  = labels[r0 + q * 4 + rr];
    }

    // 256 j-tiles of 16 cols; 8 waves -> 32 tiles/wave, unrolled x2 with
    // both tiles' loads issued before any compute (latency overlap)
    for (int i = 0; i < 32; i += 2) {
        const int col0 = (wid * 32 + i) * 16 + t;
        const int col1 = col0 + 16;
        const unsigned short* b0 = Rb + (size_t)col0 * D + q * 8;
        const unsigned short* b1 = Rb + (size_t)col1 * D + q * 8;
        bf16x8 f0[4], f1[4];
#pragma unroll
        for (int kq = 0; kq < 4; ++kq) f0[kq] = *(const bf16x8*)(b0 + kq * 32);
#pragma unroll
        for (int kq = 0; kq < 4; ++kq) f1[kq] = *(const bf16x8*)(b1 + kq * 32);
        const float sqc0 = sq[col0], sqc1 = sq[col1];
        const int   lc0  = labels[col0], lc1 = labels[col1];

        f32x4 a0 = (f32x4)0.0f, a1 = (f32x4)0.0f;
#pragma unroll
        for (int kq = 0; kq < 4; ++kq)
            a0 = __builtin_amdgcn_mfma_f32_16x16x32_bf16(af[kq], f0[kq], a0, 0, 0, 0);
#pragma unroll
        for (int kq = 0; kq < 4; ++kq)
            a1 = __builtin_amdgcn_mfma_f32_16x16x32_bf16(af[kq], f1[kq], a1, 0, 0, 0);

#pragma unroll
        for (int rr = 0; rr < 4; ++rr) {           // D: row = q*4+rr, col = t
            float d20 = fmaxf(sqa[rr] + sqc0 - 2.0f * a0[rr], 0.0f);
            float di0 = (d20 > 0.0f) ? sqrtf(d20) : 0.0f;
            float s0 = -di0 + ((la[rr] == lc0) ? 0.0f : MARGIN_F);
            S[(q * 4 + rr) * SSTR + col0] =
                (unsigned short)((xform_key(s0) + 0x8000u) >> 16);
            float d21 = fmaxf(sqa[rr] + sqc1 - 2.0f * a1[rr], 0.0f);
            float di1 = (d21 > 0.0f) ? sqrtf(d21) : 0.0f;
            float s1 = -di1 + ((la[rr] == lc1) ? 0.0f : MARGIN_F);
            S[(q * 4 + rr) * SSTR + col1] =
                (unsigned short)((xform_key(s1) + 0x8000u) >> 16);
        }
    }
    __syncthreads();                               // strip complete; cnt[] visible

    // ---- phase 2: each wave owns 2 rows; keys kv[8] from LDS; masks from table
    float facc = 0.0f;

    for (int rr2 = 0; rr2 < 2; ++rr2) {
        const int row  = wid * 2 + rr2;
        const int grow = r0 + row;
        const int li   = labels[grow];
        const uint64_t mbits = mask64[(size_t)li * 64 + lane];

        u32x4 kv[8];
#pragma unroll
        for (int qq = 0; qq < 8; ++qq)
            kv[qq] = *(u32x4*)(&S[row * SSTR + (qq * 64 + lane) * 8]);

        uint32_t t1 = 0, t2 = 0;
#pragma unroll
        for (int qq = 0; qq < 8; ++qq) {
            uint32_t u[8] = {kv[qq].x & 0xFFFFu, kv[qq].x >> 16,
                             kv[qq].y & 0xFFFFu, kv[qq].y >> 16,
                             kv[qq].z & 0xFFFFu, kv[qq].z >> 16,
                             kv[qq].w & 0xFFFFu, kv[qq].w >> 16};
#pragma unroll
            for (int c = 0; c < 8; ++c) {
                uint32_t mn = min(t1, u[c]);
                t1 = max(t1, u[c]);
                t2 = max(t2, mn);
            }
        }

        int kloc = __popcll(mbits);
#pragma unroll
        for (int off = 32; off > 0; off >>= 1) kloc += __shfl_xor(kloc, off);
        const int k = kloc;
        const float kf = (float)k;

        // ballot binary search: T = k-th largest of 128-subset (<= true k-th)
        const int kneed = min(k, 128);
        uint32_t T = 0;
#pragma unroll
        for (int b = 15; b >= 0; --b) {
            uint32_t g = T | (1u << b);
            int c = __popcll(__ballot(t1 >= g)) + __popcll(__ballot(t2 >= g));
            if (c >= kneed) T = g;
        }
        const uint32_t combT = T << 12;

        // gather candidates = {u >= T} U {matches}; comb = (u<<12)|(4095-j)
#pragma unroll
        for (int qq = 0; qq < 8; ++qq) {
            uint32_t u[8] = {kv[qq].x & 0xFFFFu, kv[qq].x >> 16,
                             kv[qq].y & 0xFFFFu, kv[qq].y >> 16,
                             kv[qq].z & 0xFFFFu, kv[qq].z >> 16,
                             kv[qq].w & 0xFFFFu, kv[qq].w >> 16};
            int jb = (qq * 64 + lane) * 8;
#pragma unroll
            for (int c = 0; c < 8; ++c) {
                int e = qq * 8 + c;
                uint32_t m = (uint32_t)((mbits >> e) & 1);
                if (u[c] >= T || m) {
                    int p = atomicAdd(&cnt[row], 1);
                    if (p < CW)
                        cand_c[row][p] = (u[c] << 12) | (uint32_t)(4095 - (jb + c)) | (m << 31);
                }
            }
        }
        const int ncand = min(cnt[row], CW);

        // candidate-internal exact ranks for u >= T (every beater is a candidate)
        for (int s = lane; s < ncand; s += 64) {
            uint32_t cs = cand_c[row][s];
            uint32_t comb = cs & 0x7FFFFFFFu;
            int m = (int)(cs >> 31);
            if (comb >= combT) {
                int c2 = 0;
                for (int c = 0; c < ncand; ++c)
                    c2 += ((cand_c[row][c] & 0x7FFFFFFFu) > comb) ? 1 : 0;
                int rank = 1 + c2;
                float v = unxform16(comb >> 12);
                if (!m && rank <= k)
                    facc += v * (0.5f + ((kf - (float)rank + 1.0f) / kf) * 0.5f);
                else if (m && rank > k)
                    facc -= v * (0.5f + (((float)rank - kf) / (float)(B - k)) * 0.5f);
            }
        }

        // below-T matches (rank > k guaranteed): register scans, batch 8
        uint32_t pa0, pa1, pa2, pa3, pa4, pa5, pa6, pa7;
        pa0 = pa1 = pa2 = pa3 = pa4 = pa5 = pa6 = pa7 = 0xFFFFFFFFu;
        int np = 0;
        for (int c = 0; c <= ncand; ++c) {
            bool fl = (c == ncand);
            if (!fl) {
                uint32_t cc_ = cand_c[row][c];
                if ((cc_ & 0x80000000u) && (cc_ & 0x7FFFFFFFu) < combT) {
                    uint32_t comb = cc_ & 0x7FFFFFFFu;
                    if      (np == 0) pa0 = comb;
                    else if (np == 1) pa1 = comb;
                    else if (np == 2) pa2 = comb;
                    else if (np == 3) pa3 = comb;
                    else if (np == 4) pa4 = comb;
                    else if (np == 5) pa5 = comb;
                    else if (np == 6) pa6 = comb;
                    else              pa7 = comb;
                    ++np;
                    fl = (np == 8);
                }
            }
            if (fl && np > 0) {
                int c0 = 0, c1 = 0, c2 = 0, c3 = 0, c4 = 0, c5 = 0, c6 = 0, c7 = 0;
#pragma unroll
                for (int qq = 0; qq < 8; ++qq) {
                    uint32_t u[8] = {kv[qq].x & 0xFFFFu, kv[qq].x >> 16,
                                     kv[qq].y & 0xFFFFu, kv[qq].y >> 16,
                                     kv[qq].z & 0xFFFFu, kv[qq].z >> 16,
                                     kv[qq].w & 0xFFFFu, kv[qq].w >> 16};
                    int jb = (qq * 64 + lane) * 8;
#pragma unroll
                    for (int cc = 0; cc < 8; ++cc) {
                        uint32_t comb_e = (u[cc] << 12) | (uint32_t)(4095 - (jb + cc));
                        c0 += (comb_e > pa0) ? 1 : 0;
                        c1 += (comb_e > pa1) ? 1 : 0;
                        c2 += (comb_e > pa2) ? 1 : 0;
                        c3 += (comb_e > pa3) ? 1 : 0;
                        c4 += (comb_e > pa4) ? 1 : 0;
                        c5 += (comb_e > pa5) ? 1 : 0;
                        c6 += (comb_e > pa6) ? 1 : 0;
                        c7 += (comb_e > pa7) ? 1 : 0;
                    }
                }
#pragma unroll
                for (int off = 32; off > 0; off >>= 1) {
                    c0 += __shfl_xor(c0, off); c1 += __shfl_xor(c1, off);
                    c2 += __shfl_xor(c2, off); c3 += __shfl_xor(c3, off);
                    c4 += __shfl_xor(c4, off); c5 += __shfl_xor(c5, off);
                    c6 += __shfl_xor(c6, off); c7 += __shfl_xor(c7, off);
                }
                if (lane == 0) {
                    int rk[8] = {1 + c0, 1 + c1, 1 + c2, 1 + c3,
                                 1 + c4, 1 + c5, 1 + c6, 1 + c7};
                    uint32_t pp[8] = {pa0, pa1, pa2, pa3, pa4, pa5, pa6, pa7};
                    for (int ii = 0; ii < np; ++ii) {
                        float v = unxform16(pp[ii] >> 12);
                        facc -= v * (0.5f + (((float)rk[ii] - kf) / (float)(B - k)) * 0.5f);
                    }
                }
                pa0 = pa1 = pa2 = pa3 = pa4 = pa5 = pa6 = pa7 = 0xFFFFFFFFu;
                np = 0;
            }
        }
    }

#pragma unroll
    for (int off = 32; off > 0; off >>= 1) facc += __shfl_xor(facc, off);
    if (lane == 0) atomicAdd(out, facc);
}

extern "C" void kernel_launch(void* const* d_in, const int* in_sizes, int n_in,
                              void* d_out, int out_size, void* d_ws, size_t ws_size,
                              hipStream_t stream) {
    const float* R      = (const float*)d_in[0];
    const int*   labels = (const int*)d_in[1];
    float* out = (float*)d_out;

    float*              sq   = (float*)d_ws;                                 // 16 KB
    unsigned short*     Rb   = (unsigned short*)((char*)d_ws + 16 * 1024);   // 1 MB
    unsigned long long* mask = (unsigned long long*)((char*)d_ws + 16 * 1024 + 1024 * 1024);

    hipLaunchKernelGGL(prep_kernel, dim3(B / 4), dim3(256), 0, stream,
                       R, labels, sq, Rb, mask, out);
    hipLaunchKernelGGL(fused_loss, dim3(B / ROWS), dim3(512), 0, stream,
                       Rb, sq, labels, mask, out);
}

// Round 14
// 135.383 us; speedup vs baseline: 1.2967x; 1.0275x over previous
//
#include <hip/hip_runtime.h>
#include <cstdint>
#include <cstddef>

#define B 4096
#define D 128
#define MARGIN_F 0.2f
#define CW 256            // per-row candidate capacity
#define ROWS 16           // rows per block
#define SSTR 4104         // key-strip stride (ushorts): rows 16B-aligned, bank-skewed

typedef short bf16x8 __attribute__((ext_vector_type(8)));
typedef float f32x4 __attribute__((ext_vector_type(4)));
typedef uint32_t u32x4 __attribute__((ext_vector_type(4)));

// order-preserving float->uint (ascending uint == ascending float)
__device__ __forceinline__ uint32_t xform_key(float f) {
    uint32_t u = __float_as_uint(f);
    return u ^ (uint32_t)((((int32_t)u) >> 31) | 0x80000000);
}
// decode 16-bit truncated key (bucket center under round-to-nearest encode)
__device__ __forceinline__ float unxform16(uint32_t k16) {
    uint32_t u = k16 << 16;
    u = (u & 0x80000000u) ? (u ^ 0x80000000u) : ~u;
    return __uint_as_float(u);
}
__device__ __forceinline__ unsigned short f2bf(float f) {   // round-nearest-even
    uint32_t u = __float_as_uint(f);
    return (unsigned short)((u + 0x7FFFu + ((u >> 16) & 1u)) >> 16);
}

// fused: zero out, sq[i] = ||R[i]||^2, R -> Rb (bf16 rne)
__global__ __launch_bounds__(256) void prep_kernel(const float* __restrict__ R,
                                                   float* __restrict__ sq,
                                                   unsigned short* __restrict__ Rb,
                                                   float* __restrict__ out) {
    if (blockIdx.x == 0 && threadIdx.x == 0) out[0] = 0.0f;
    int wave = threadIdx.x >> 6;
    int lane = threadIdx.x & 63;
    int row  = blockIdx.x * 4 + wave;
    const float2* R2 = (const float2*)R + (size_t)row * (D / 2);
    float2 v = R2[lane];
    ushort2 o; o.x = f2bf(v.x); o.y = f2bf(v.y);
    *(ushort2*)(Rb + (size_t)row * D + lane * 2) = o;
    float s = v.x * v.x + v.y * v.y;
#pragma unroll
    for (int off = 32; off > 0; off >>= 1) s += __shfl_down(s, off);
    if (lane == 0) sq[row] = s;
}

// FUSED: 16 rows/block. Phase 1: MFMA gram (A = own rows in registers,
// B = Rb streamed from L2) + dist/margin -> 16-bit keys in a 128KB LDS strip.
// Phase 2: per-wave threshold/rank machinery reading keys from LDS.
// (r10 configuration — empirically best; r11/r12/r13 deviations all regressed)
__global__ __launch_bounds__(512) void fused_loss(const unsigned short* __restrict__ Rb,
                                                  const float* __restrict__ sq,
                                                  const int* __restrict__ labels,
                                                  float* __restrict__ out) {
    __shared__ unsigned short S[ROWS * SSTR];      // 131,328 B key strip
    __shared__ uint32_t cand_c[ROWS][CW];          // 16 KB: comb | (match<<31)
    __shared__ int cnt[ROWS];

    const int tid  = threadIdx.x;
    const int wid  = tid >> 6, lane = tid & 63;
    const int q    = lane >> 4, t = lane & 15;
    const int r0   = blockIdx.x * ROWS;

    if (tid < ROWS) cnt[tid] = 0;

    // ---- phase 1: A fragments for the block's 16 rows (held in registers)
    bf16x8 af[4];
    const unsigned short* baseA = Rb + (size_t)(r0 + t) * D + q * 8;
#pragma unroll
    for (int kq = 0; kq < 4; ++kq)
        af[kq] = *(const bf16x8*)(baseA + kq * 32);

    float sqa[4]; int la[4];                       // epilogue row scalars (row = q*4+rr)
#pragma unroll
    for (int rr = 0; rr < 4; ++rr) {
        sqa[rr] = sq[r0 + q * 4 + rr];
        la[rr]  = labels[r0 + q * 4 + rr];
    }

    // 256 j-tiles of 16 cols; 8 waves -> 32 tiles/wave
    for (int i = 0; i < 32; ++i) {
        const int jt  = wid * 32 + i;
        const int col = jt * 16 + t;
        const unsigned short* baseB = Rb + (size_t)col * D + q * 8;
        bf16x8 bfr[4];
#pragma unroll
        for (int kq = 0; kq < 4; ++kq)
            bfr[kq] = *(const bf16x8*)(baseB + kq * 32);
        f32x4 acc = (f32x4)0.0f;
#pragma unroll
        for (int kq = 0; kq < 4; ++kq)
            acc = __builtin_amdgcn_mfma_f32_16x16x32_bf16(af[kq], bfr[kq], acc, 0, 0, 0);

        const float sqc = sq[col];
        const int   lc  = labels[col];
#pragma unroll
        for (int rr = 0; rr < 4; ++rr) {           // D: row = q*4+rr, col = t
            float g  = acc[rr];
            float d2 = fmaxf(sqa[rr] + sqc - 2.0f * g, 0.0f);
            float dist = (d2 > 0.0f) ? sqrtf(d2) : 0.0f;
            float s = -dist + ((la[rr] == lc) ? 0.0f : MARGIN_F);
            uint32_t key = xform_key(s);           // sim <= 0.2 -> no ovf on +0x8000
            S[(q * 4 + rr) * SSTR + col] = (unsigned short)((key + 0x8000u) >> 16);
        }
    }
    __syncthreads();                               // strip complete; cnt[] visible

    // ---- phase 2: each wave owns 2 rows; keys kv[8] from LDS (b128, aligned)
    float facc = 0.0f;
    const int4* lv = (const int4*)labels;

    for (int rr2 = 0; rr2 < 2; ++rr2) {
        const int row  = wid * 2 + rr2;
        const int grow = r0 + row;
        const int li   = labels[grow];

        u32x4 kv[8];
#pragma unroll
        for (int qq = 0; qq < 8; ++qq)
            kv[qq] = *(u32x4*)(&S[row * SSTR + (qq * 64 + lane) * 8]);

        uint64_t mbits = 0;
        uint32_t t1 = 0, t2 = 0;
#pragma unroll
        for (int qq = 0; qq < 8; ++qq) {
            const int lb = (qq * 64 + lane) * 2;
            int4 la4 = lv[lb], lc4 = lv[lb + 1];
            uint32_t u[8] = {kv[qq].x & 0xFFFFu, kv[qq].x >> 16,
                             kv[qq].y & 0xFFFFu, kv[qq].y >> 16,
                             kv[qq].z & 0xFFFFu, kv[qq].z >> 16,
                             kv[qq].w & 0xFFFFu, kv[qq].w >> 16};
#pragma unroll
            for (int c = 0; c < 8; ++c) {
                uint32_t mn = min(t1, u[c]);
                t1 = max(t1, u[c]);
                t2 = max(t2, mn);
            }
            mbits |= (uint64_t)(la4.x == li) << (qq * 8 + 0);
            mbits |= (uint64_t)(la4.y == li) << (qq * 8 + 1);
            mbits |= (uint64_t)(la4.z == li) << (qq * 8 + 2);
            mbits |= (uint64_t)(la4.w == li) << (qq * 8 + 3);
            mbits |= (uint64_t)(lc4.x == li) << (qq * 8 + 4);
            mbits |= (uint64_t)(lc4.y == li) << (qq * 8 + 5);
            mbits |= (uint64_t)(lc4.z == li) << (qq * 8 + 6);
            mbits |= (uint64_t)(lc4.w == li) << (qq * 8 + 7);
        }

        int kloc = __popcll(mbits);
#pragma unroll
        for (int off = 32; off > 0; off >>= 1) kloc += __shfl_xor(kloc, off);
        const int k = kloc;
        const float kf = (float)k;

        // ballot binary search: T = k-th largest of 128-subset (<= true k-th)
        const int kneed = min(k, 128);
        uint32_t T = 0;
#pragma unroll
        for (int b = 15; b >= 0; --b) {
            uint32_t g = T | (1u << b);
            int c = __popcll(__ballot(t1 >= g)) + __popcll(__ballot(t2 >= g));
            if (c >= kneed) T = g;
        }
        const uint32_t combT = T << 12;

        // gather candidates = {u >= T} U {matches}; comb = (u<<12)|(4095-j)
#pragma unroll
        for (int qq = 0; qq < 8; ++qq) {
            uint32_t u[8] = {kv[qq].x & 0xFFFFu, kv[qq].x >> 16,
                             kv[qq].y & 0xFFFFu, kv[qq].y >> 16,
                             kv[qq].z & 0xFFFFu, kv[qq].z >> 16,
                             kv[qq].w & 0xFFFFu, kv[qq].w >> 16};
            int jb = (qq * 64 + lane) * 8;
#pragma unroll
            for (int c = 0; c < 8; ++c) {
                int e = qq * 8 + c;
                uint32_t m = (uint32_t)((mbits >> e) & 1);
                if (u[c] >= T || m) {
                    int p = atomicAdd(&cnt[row], 1);
                    if (p < CW)
                        cand_c[row][p] = (u[c] << 12) | (uint32_t)(4095 - (jb + c)) | (m << 31);
                }
            }
        }
        const int ncand = min(cnt[row], CW);

        // candidate-internal exact ranks for u >= T (every beater is a candidate)
        for (int s = lane; s < ncand; s += 64) {
            uint32_t cs = cand_c[row][s];
            uint32_t comb = cs & 0x7FFFFFFFu;
            int m = (int)(cs >> 31);
            if (comb >= combT) {
                int c2 = 0;
                for (int c = 0; c < ncand; ++c)
                    c2 += ((cand_c[row][c] & 0x7FFFFFFFu) > comb) ? 1 : 0;
                int rank = 1 + c2;
                float v = unxform16(comb >> 12);
                if (!m && rank <= k)
                    facc += v * (0.5f + ((kf - (float)rank + 1.0f) / kf) * 0.5f);
                else if (m && rank > k)
                    facc -= v * (0.5f + (((float)rank - kf) / (float)(B - k)) * 0.5f);
            }
        }

        // below-T matches (rank > k guaranteed): register scans, batch 4
        uint32_t p0 = 0xFFFFFFFFu, p1 = 0xFFFFFFFFu, p2 = 0xFFFFFFFFu, p3 = 0xFFFFFFFFu;
        int np = 0;
        for (int c = 0; c <= ncand; ++c) {
            bool flushit = (c == ncand);
            if (!flushit) {
                uint32_t cc_ = cand_c[row][c];
                if ((cc_ & 0x80000000u) && (cc_ & 0x7FFFFFFFu) < combT) {
                    uint32_t comb = cc_ & 0x7FFFFFFFu;
                    if (np == 0) p0 = comb; else if (np == 1) p1 = comb;
                    else if (np == 2) p2 = comb; else p3 = comb;
                    ++np;
                    flushit = (np == 4);
                }
            }
            if (flushit && np > 0) {
                int c0 = 0, c1 = 0, c2 = 0, c3 = 0;
#pragma unroll
                for (int qq = 0; qq < 8; ++qq) {
                    uint32_t u[8] = {kv[qq].x & 0xFFFFu, kv[qq].x >> 16,
                                     kv[qq].y & 0xFFFFu, kv[qq].y >> 16,
                                     kv[qq].z & 0xFFFFu, kv[qq].z >> 16,
                                     kv[qq].w & 0xFFFFu, kv[qq].w >> 16};
                    int jb = (qq * 64 + lane) * 8;
#pragma unroll
                    for (int cc = 0; cc < 8; ++cc) {
                        uint32_t comb_e = (u[cc] << 12) | (uint32_t)(4095 - (jb + cc));
                        c0 += (comb_e > p0) ? 1 : 0;
                        c1 += (comb_e > p1) ? 1 : 0;
                        c2 += (comb_e > p2) ? 1 : 0;
                        c3 += (comb_e > p3) ? 1 : 0;
                    }
                }
#pragma unroll
                for (int off = 32; off > 0; off >>= 1) {
                    c0 += __shfl_xor(c0, off); c1 += __shfl_xor(c1, off);
                    c2 += __shfl_xor(c2, off); c3 += __shfl_xor(c3, off);
                }
                if (lane == 0) {
                    int rk[4] = {1 + c0, 1 + c1, 1 + c2, 1 + c3};
                    uint32_t pp[4] = {p0, p1, p2, p3};
                    for (int ii = 0; ii < np; ++ii) {
                        float v = unxform16(pp[ii] >> 12);
                        facc -= v * (0.5f + (((float)rk[ii] - kf) / (float)(B - k)) * 0.5f);
                    }
                }
                p0 = p1 = p2 = p3 = 0xFFFFFFFFu;
                np = 0;
            }
        }
    }

#pragma unroll
    for (int off = 32; off > 0; off >>= 1) facc += __shfl_xor(facc, off);
    if (lane == 0) atomicAdd(out, facc);
}

extern "C" void kernel_launch(void* const* d_in, const int* in_sizes, int n_in,
                              void* d_out, int out_size, void* d_ws, size_t ws_size,
                              hipStream_t stream) {
    const float* R      = (const float*)d_in[0];
    const int*   labels = (const int*)d_in[1];
    float* out = (float*)d_out;

    float*          sq = (float*)d_ws;                               // 16 KB
    unsigned short* Rb = (unsigned short*)((char*)d_ws + 16 * 1024); // 1 MB

    hipLaunchKernelGGL(prep_kernel, dim3(B / 4), dim3(256), 0, stream, R, sq, Rb, out);
    hipLaunchKernelGGL(fused_loss, dim3(B / ROWS), dim3(512), 0, stream,
                       Rb, sq, labels, out);
}